// Round 8
// baseline (1064.813 us; speedup 1.0000x reference)
//
#include <hip/hip_runtime.h>
#include <hip/hip_bf16.h>

typedef __bf16 bf16;
typedef __bf16 bf16x8 __attribute__((ext_vector_type(8)));
typedef float f32x4 __attribute__((ext_vector_type(4)));
typedef unsigned int u32;

#define D_    2048
#define NSEQ  4096
#define BATCH 2
#define CH    1024   // recurrence chunk (math is chunk-size invariant)
#define TC    4      // chunks per batch
#define MROWS 8192   // BATCH*NSEQ

__device__ __forceinline__ void gload16(const bf16* g, bf16* l) {
  __builtin_amdgcn_global_load_lds(
      (const __attribute__((address_space(1))) u32*)g,
      (__attribute__((address_space(3))) u32*)l, 16, 0, 0);
}

// ================= 128^2 m97-style core (recurrence kernels; unchanged) =====

struct SmemTiles {
  alignas(16) bf16 As[128 * 32];
  alignas(16) bf16 Bs[128 * 32];
};

__device__ __forceinline__ void gemm_core(SmemTiles& sm, const bf16* A, int lda,
                                          const bf16* B, int ldb, int K,
                                          f32x4 acc[4][4]) {
  const int tid = threadIdx.x;
  const int lane = tid & 63;
  const int wave = tid >> 6;
  const int wr = wave >> 1, wc = wave & 1;
  const int l15 = lane & 15, kl = lane >> 4;
  const bf16* Ar = sm.As + (wr * 64 + l15) * 32 + kl * 8;
  const bf16* Br = sm.Bs + (wc * 64 + l15) * 32 + kl * 8;

  for (int k0 = 0; k0 < K; k0 += 32) {
#pragma unroll
    for (int it = 0; it < 2; ++it) {
      int c = it * 256 + tid;
      int r = c >> 2;
      int co = (c & 3) << 3;
      gload16(A + r * lda + k0 + co, sm.As + c * 8);
      gload16(B + r * ldb + k0 + co, sm.Bs + c * 8);
    }
    __syncthreads();
    bf16x8 a[4], b[4];
#pragma unroll
    for (int m = 0; m < 4; ++m) a[m] = *(const bf16x8*)(Ar + m * 16 * 32);
#pragma unroll
    for (int n = 0; n < 4; ++n) b[n] = *(const bf16x8*)(Br + n * 16 * 32);
#pragma unroll
    for (int m = 0; m < 4; ++m)
#pragma unroll
      for (int n = 0; n < 4; ++n)
        acc[m][n] = __builtin_amdgcn_mfma_f32_16x16x32_bf16(a[m], b[n], acc[m][n], 0, 0, 0);
    __syncthreads();
  }
}

#define EPILOGUE_VARS                              \
  const int lane = threadIdx.x & 63;               \
  const int wave = threadIdx.x >> 6;               \
  const int wr = wave >> 1, wc = wave & 1;         \
  const int l15 = lane & 15, kl = lane >> 4;

// ================= 256^2 4-phase pipelined core (T3+T4+T5) ==================
//
// 512 threads = 8 waves (2M x 4N); per-wave C sub-tile 128x64; BK=64.
// LDS: subtile-linear slabs (bank-conflict-free, measured 0 in round 6).
// Schedule per K-tile t (read buf t&1), 4 phases; tile t+1 staged into the
// OPPOSITE buffer, 1 half-tile/phase.
//
// RACE FIX (round 7 -> 8): vmcnt is PER-WAVE, but fragments are read from
// slabs staged by OTHER waves. Phase 0 must therefore be:
//   stage; vmcnt(2); s_barrier  <- all waves validated tile t's loads
//   ds_read frags; lgkmcnt(0); MFMA; s_barrier
// (round 7 issued the ds_reads BEFORE the validation barrier -> stale LDS).
// Phases 1-3 read buf t&1 (validated at phase 0's barrier) so their reads may
// precede their begin-barrier safely; stage writes of buf (t+1)&1 are safe
// because all tile-(t-1) readers drained (each wave's lgkmcnt(0) precedes the
// end barrier of tile t-1 phase 3).
// vmcnt(2) accounting: at phase 0, outstanding = 2 (t+1 A-h0, just issued)
// + 8 (tile t, issued during t-1); waiting to 2 completes all of tile t.

struct Smem256 {
  alignas(16) bf16 A[2][256 * 64];
  alignas(16) bf16 B[2][256 * 64];
};

__device__ __forceinline__ void stage_half(bf16* lds, const bf16* g, int ld,
                                           int k0, int h, int wave, int lane) {
  const int r16 = lane & 15, c8 = lane >> 4;
  const int mb = h * 8 + wave;
  const bf16* gp = g + (size_t)(mb * 16 + r16) * ld + k0 + c8 * 8;
  bf16* lp = lds + mb * 1024 + lane * 8;
  gload16(gp, lp);
  gload16(gp + 32, lp + 512);
}

#define PHASE_SYNC_BEGIN()                                  \
  __builtin_amdgcn_s_barrier();                             \
  asm volatile("s_waitcnt lgkmcnt(0)" ::: "memory");        \
  __builtin_amdgcn_sched_barrier(0);                        \
  __builtin_amdgcn_s_setprio(1);

#define PHASE_SYNC_END()                                    \
  __builtin_amdgcn_s_setprio(0);                            \
  __builtin_amdgcn_s_barrier();

__device__ __forceinline__ void gemm256_core(Smem256& sm, const bf16* A,
                                             int lda, const bf16* B, int ldb,
                                             int K, f32x4 acc[8][4]) {
  const int tid = threadIdx.x;
  const int wave = tid >> 6, lane = tid & 63;
  const int wr = wave >> 2, wc = wave & 3;
  const int NT = K >> 6;
  if (NT <= 0) return;

  // prologue: stage all 4 halves of tile 0 into buf 0
  stage_half(sm.A[0], A, lda, 0, 0, wave, lane);
  stage_half(sm.A[0], A, lda, 0, 1, wave, lane);
  stage_half(sm.B[0], B, ldb, 0, 0, wave, lane);
  stage_half(sm.B[0], B, ldb, 0, 1, wave, lane);

  const int aoff = wr * 8192 + lane * 8;  // A slab base for this wave's half
  const int boff = wc * 4096 + lane * 8;  // B slab base for this wave's quarter

  for (int t = 0; t < NT; ++t) {
    const bf16* Ab = sm.A[t & 1];
    const bf16* Bb = sm.B[t & 1];
    bf16* An = sm.A[(t + 1) & 1];
    bf16* Bn = sm.B[(t + 1) & 1];
    const bool pf = (t + 1 < NT);
    const int kn = (t + 1) * 64;
    bf16x8 av[4], bv[4];

    // ---------- phase 0: stage A-h0(t+1); validate tile t for ALL waves;
    //            then frags b@k0 + a(m0-3)@k0; MFMA quadrant
    if (pf) {
      stage_half(An, A, lda, kn, 0, wave, lane);
      asm volatile("s_waitcnt vmcnt(2)" ::: "memory");  // own tile-t loads done
    } else {
      asm volatile("s_waitcnt vmcnt(0)" ::: "memory");
    }
    __builtin_amdgcn_s_barrier();          // every wave's tile-t loads done
    __builtin_amdgcn_sched_barrier(0);     // keep ds_reads below the barrier
#pragma unroll
    for (int nf = 0; nf < 4; ++nf) bv[nf] = *(const bf16x8*)&Bb[boff + nf * 1024];
#pragma unroll
    for (int mf = 0; mf < 4; ++mf) av[mf] = *(const bf16x8*)&Ab[aoff + mf * 1024];
    asm volatile("s_waitcnt lgkmcnt(0)" ::: "memory");
    __builtin_amdgcn_sched_barrier(0);
    __builtin_amdgcn_s_setprio(1);
#pragma unroll
    for (int mf = 0; mf < 4; ++mf)
#pragma unroll
      for (int nf = 0; nf < 4; ++nf)
        acc[mf][nf] = __builtin_amdgcn_mfma_f32_16x16x32_bf16(av[mf], bv[nf],
                                                              acc[mf][nf], 0, 0, 0);
    PHASE_SYNC_END()

    // ---------- phase 1: stage A-h1(t+1); frags a(m4-7)@k0 (b@k0 reused)
    if (pf) stage_half(An, A, lda, kn, 1, wave, lane);
#pragma unroll
    for (int mf = 0; mf < 4; ++mf)
      av[mf] = *(const bf16x8*)&Ab[aoff + (mf + 4) * 1024];
    PHASE_SYNC_BEGIN()
#pragma unroll
    for (int mf = 0; mf < 4; ++mf)
#pragma unroll
      for (int nf = 0; nf < 4; ++nf)
        acc[mf + 4][nf] = __builtin_amdgcn_mfma_f32_16x16x32_bf16(av[mf], bv[nf],
                                                                  acc[mf + 4][nf], 0, 0, 0);
    PHASE_SYNC_END()

    // ---------- phase 2: stage B-h0(t+1); frags b@k1 + a(m0-3)@k1
    if (pf) stage_half(Bn, B, ldb, kn, 0, wave, lane);
#pragma unroll
    for (int nf = 0; nf < 4; ++nf)
      bv[nf] = *(const bf16x8*)&Bb[boff + nf * 1024 + 512];
#pragma unroll
    for (int mf = 0; mf < 4; ++mf)
      av[mf] = *(const bf16x8*)&Ab[aoff + mf * 1024 + 512];
    PHASE_SYNC_BEGIN()
#pragma unroll
    for (int mf = 0; mf < 4; ++mf)
#pragma unroll
      for (int nf = 0; nf < 4; ++nf)
        acc[mf][nf] = __builtin_amdgcn_mfma_f32_16x16x32_bf16(av[mf], bv[nf],
                                                              acc[mf][nf], 0, 0, 0);
    PHASE_SYNC_END()

    // ---------- phase 3: stage B-h1(t+1); frags a(m4-7)@k1 (b@k1 reused)
    if (pf) stage_half(Bn, B, ldb, kn, 1, wave, lane);
#pragma unroll
    for (int mf = 0; mf < 4; ++mf)
      av[mf] = *(const bf16x8*)&Ab[aoff + (mf + 4) * 1024 + 512];
    PHASE_SYNC_BEGIN()
#pragma unroll
    for (int mf = 0; mf < 4; ++mf)
#pragma unroll
      for (int nf = 0; nf < 4; ++nf)
        acc[mf + 4][nf] = __builtin_amdgcn_mfma_f32_16x16x32_bf16(av[mf], bv[nf],
                                                                  acc[mf + 4][nf], 0, 0, 0);
    PHASE_SYNC_END()
  }
}

#define EPILOGUE256_VARS                           \
  const int lane = threadIdx.x & 63;               \
  const int wave = threadIdx.x >> 6;               \
  const int wr = wave >> 2, wc = wave & 3;         \
  const int l15 = lane & 15, kl = lane >> 4;

// T1: XCD row-band swizzle for the (8, 32) big-GEMM grids (nwg=256, %8==0).
__device__ __forceinline__ void swz_block(int& bx, int& by) {
  int lin = blockIdx.y * gridDim.x + blockIdx.x;   // 0..255
  int work = (lin & 7) * 32 + (lin >> 3);          // XCD gets 4 rows x 8 cols
  bx = work & 7;
  by = work >> 3;
}

// ---------------- elementwise kernels ----------------

__global__ __launch_bounds__(256) void k_f2b(const float* __restrict__ in,
                                             bf16* __restrict__ out) {
  int i = (blockIdx.x * 256 + threadIdx.x) * 8;
  float4 a = *(const float4*)(in + i);
  float4 b = *(const float4*)(in + i + 4);
  bf16x8 o;
  o[0] = (bf16)a.x; o[1] = (bf16)a.y; o[2] = (bf16)a.z; o[3] = (bf16)a.w;
  o[4] = (bf16)b.x; o[5] = (bf16)b.y; o[6] = (bf16)b.z; o[7] = (bf16)b.w;
  *(bf16x8*)(out + i) = o;
}

__global__ __launch_bounds__(256) void k_rms(const float* __restrict__ x,
                                             bf16* __restrict__ xn) {
  const int row = blockIdx.x;
  const int tid = threadIdx.x;
  const float* xr = x + (size_t)row * D_;
  float4 a = *(const float4*)(xr + tid * 8);
  float4 b = *(const float4*)(xr + tid * 8 + 4);
  float ss = a.x * a.x + a.y * a.y + a.z * a.z + a.w * a.w +
             b.x * b.x + b.y * b.y + b.z * b.z + b.w * b.w;
#pragma unroll
  for (int o = 32; o > 0; o >>= 1) ss += __shfl_xor(ss, o, 64);
  __shared__ float red[4];
  if ((tid & 63) == 0) red[tid >> 6] = ss;
  __syncthreads();
  float tot = red[0] + red[1] + red[2] + red[3];
  float sc = rsqrtf(tot * (1.f / D_) + 1.1920928955078125e-07f);
  bf16x8 o;
  o[0] = (bf16)(a.x * sc); o[1] = (bf16)(a.y * sc);
  o[2] = (bf16)(a.z * sc); o[3] = (bf16)(a.w * sc);
  o[4] = (bf16)(b.x * sc); o[5] = (bf16)(b.y * sc);
  o[6] = (bf16)(b.z * sc); o[7] = (bf16)(b.w * sc);
  *(bf16x8*)(xn + (size_t)row * D_ + tid * 8) = o;
}

// ---------------- big dense GEMMs on the 256^2 pipelined core ----------------

// C = act(xn @ W^T); SMODE bit0: store normal, bit1: store transposed [B][D][N]
template <int ACT, int SMODE>
__global__ __launch_bounds__(512, 2) void k_proj2(const bf16* __restrict__ xn,
                                                  const bf16* __restrict__ W,
                                                  bf16* __restrict__ Cn,
                                                  bf16* __restrict__ Ct) {
  __shared__ Smem256 sm;
  int bx, by;
  swz_block(bx, by);
  const int row0 = by * 256, col0 = bx * 256;
  f32x4 acc[8][4] = {};
  gemm256_core(sm, xn + (size_t)row0 * D_, D_, W + (size_t)col0 * D_, D_, D_, acc);
  EPILOGUE256_VARS
#pragma unroll
  for (int mf = 0; mf < 8; ++mf)
#pragma unroll
    for (int nf = 0; nf < 4; ++nf)
#pragma unroll
      for (int j = 0; j < 4; ++j) {
        int r = row0 + wr * 128 + mf * 16 + kl * 4 + j;
        int c = col0 + wc * 64 + nf * 16 + l15;
        float v = acc[mf][nf][j];
        if (ACT == 1) v = v / (1.f + __expf(-v));        // silu
        if (ACT == 2) v = 1.f / (1.f + __expf(-v));      // sigmoid
        bf16 ob = (bf16)v;
        if (SMODE & 1) Cn[(size_t)r * D_ + c] = ob;
        if (SMODE & 2)
          Ct[((size_t)(r >> 12) * D_ + c) * NSEQ + (r & (NSEQ - 1))] = ob;
      }
}

// out = og @ Wp^T (fp32 store)
__global__ __launch_bounds__(512, 2) void k_final2(const bf16* __restrict__ og,
                                                   const bf16* __restrict__ Wp,
                                                   float* __restrict__ out) {
  __shared__ Smem256 sm;
  int bx, by;
  swz_block(bx, by);
  const int row0 = by * 256, col0 = bx * 256;
  f32x4 acc[8][4] = {};
  gemm256_core(sm, og + (size_t)row0 * D_, D_, Wp + (size_t)col0 * D_, D_, D_, acc);
  EPILOGUE256_VARS
#pragma unroll
  for (int mf = 0; mf < 8; ++mf)
#pragma unroll
    for (int nf = 0; nf < 4; ++nf)
#pragma unroll
      for (int j = 0; j < 4; ++j) {
        int r = row0 + wr * 128 + mf * 16 + kl * 4 + j;
        int c = col0 + wc * 64 + nf * 16 + l15;
        out[(size_t)r * D_ + c] = acc[mf][nf][j];
      }
}

// ---------------- chunked-recurrence kernels (128^2 core, unchanged) --------

// s[z] = tril(q_t k_t^T), z = b*TC + t, chunk CH=1024.
__global__ __launch_bounds__(256) void k_scores(const bf16* __restrict__ q,
                                                const bf16* __restrict__ k,
                                                bf16* __restrict__ s) {
  const int z = blockIdx.z, b = z >> 2, t = z & 3;
  const int row0 = blockIdx.y * 128, col0 = blockIdx.x * 128;
  if (col0 > row0) return;  // strictly upper tile
  __shared__ SmemTiles sm;
  f32x4 acc[4][4] = {};
  gemm_core(sm, q + (size_t)(b * NSEQ + t * CH + row0) * D_, D_,
                k + (size_t)(b * NSEQ + t * CH + col0) * D_, D_, D_, acc);
  EPILOGUE_VARS
  bf16* sp = s + (size_t)z * CH * CH;
#pragma unroll
  for (int m = 0; m < 4; ++m)
#pragma unroll
    for (int n = 0; n < 4; ++n)
#pragma unroll
      for (int j = 0; j < 4; ++j) {
        int i = row0 + wr * 64 + m * 16 + kl * 4 + j;
        int jc = col0 + wc * 64 + n * 16 + l15;
        float v = (i >= jc) ? acc[m][n][j] : 0.f;
        sp[(size_t)i * CH + jc] = (bf16)v;
      }
}

// og[chunk rows] = s @ v  (intra-chunk; K trimmed to lower-tri extent)
__global__ __launch_bounds__(256) void k_ointra(const bf16* __restrict__ s,
                                                const bf16* __restrict__ vT,
                                                bf16* __restrict__ og) {
  __shared__ SmemTiles sm;
  const int z = blockIdx.z, b = z >> 2, t = z & 3;
  const int row0 = blockIdx.y * 128, col0 = blockIdx.x * 128;
  const int K = row0 + 128;
  f32x4 acc[4][4] = {};
  gemm_core(sm, s + (size_t)z * CH * CH + (size_t)row0 * CH, CH,
                vT + (size_t)b * D_ * NSEQ + (size_t)col0 * NSEQ + t * CH, NSEQ,
                K, acc);
  EPILOGUE_VARS
#pragma unroll
  for (int m = 0; m < 4; ++m)
#pragma unroll
    for (int n = 0; n < 4; ++n)
#pragma unroll
      for (int j = 0; j < 4; ++j) {
        int i = row0 + wr * 64 + m * 16 + kl * 4 + j;
        int c = col0 + wc * 64 + n * 16 + l15;
        og[(size_t)(b * NSEQ + t * CH + i) * D_ + c] = (bf16)acc[m][n][j];
      }
}

// og = (og + q_t @ kvT^T) * g   (Kin==0 for t==0: just gate)
__global__ __launch_bounds__(256) void k_ointer(const bf16* __restrict__ q,
                                                const bf16* __restrict__ kvb,
                                                const bf16* __restrict__ g,
                                                bf16* __restrict__ og, int t,
                                                int Kin) {
  __shared__ SmemTiles sm;
  const int b = blockIdx.z;
  const int row0 = blockIdx.y * 128, col0 = blockIdx.x * 128;
  f32x4 acc[4][4] = {};
  gemm_core(sm, q + (size_t)(b * NSEQ + t * CH + row0) * D_, D_,
                kvb + (size_t)b * D_ * D_ + (size_t)col0 * D_, D_, Kin, acc);
  EPILOGUE_VARS
#pragma unroll
  for (int m = 0; m < 4; ++m)
#pragma unroll
    for (int n = 0; n < 4; ++n)
#pragma unroll
      for (int j = 0; j < 4; ++j) {
        int i = row0 + wr * 64 + m * 16 + kl * 4 + j;
        int c = col0 + wc * 64 + n * 16 + l15;
        size_t idx = (size_t)(b * NSEQ + t * CH + i) * D_ + c;
        float v = ((float)og[idx] + acc[m][n][j]) * (float)g[idx];
        og[idx] = (bf16)v;
      }
}

// kvT[b][e][d] += sum_{j in chunk t} v[j][e] k[j][d]
__global__ __launch_bounds__(256) void k_update(const bf16* __restrict__ vT,
                                                const bf16* __restrict__ kT,
                                                float* __restrict__ kvf,
                                                bf16* __restrict__ kvb, int t) {
  __shared__ SmemTiles sm;
  const int b = blockIdx.z;
  const int row0 = blockIdx.y * 128, col0 = blockIdx.x * 128;
  f32x4 acc[4][4] = {};
  gemm_core(sm, vT + (size_t)b * D_ * NSEQ + (size_t)row0 * NSEQ + t * CH, NSEQ,
                kT + (size_t)b * D_ * NSEQ + (size_t)col0 * NSEQ + t * CH, NSEQ,
                CH, acc);
  EPILOGUE_VARS
#pragma unroll
  for (int m = 0; m < 4; ++m)
#pragma unroll
    for (int n = 0; n < 4; ++n)
#pragma unroll
      for (int j = 0; j < 4; ++j) {
        int e = row0 + wr * 64 + m * 16 + kl * 4 + j;
        int d = col0 + wc * 64 + n * 16 + l15;
        size_t idx = (size_t)b * D_ * D_ + (size_t)e * D_ + d;
        float v = kvf[idx] + acc[m][n][j];
        kvf[idx] = v;
        kvb[idx] = (bf16)v;
      }
}

// ---------------- host launch ----------------
//
// Workspace plan (153 MiB): xn/og 32 | kT 32 | vT 32 | {k->kvf} 32 |
// {s->kvb} 16.78 | Wb 8.  q,g live in d_out (dead before k_final2).

extern "C" void kernel_launch(void* const* d_in, const int* in_sizes, int n_in,
                              void* d_out, int out_size, void* d_ws, size_t ws_size,
                              hipStream_t stream) {
  (void)in_sizes; (void)n_in; (void)out_size; (void)ws_size;
  const float* x  = (const float*)d_in[0];
  const float* Wq = (const float*)d_in[1];
  const float* Wk = (const float*)d_in[2];
  const float* Wv = (const float*)d_in[3];
  const float* Wg = (const float*)d_in[4];
  const float* Wp = (const float*)d_in[5];
  float* out = (float*)d_out;

  char* p = (char*)d_ws;
  auto take = [&](size_t bytes) {
    char* r = p;
    p += (bytes + 255) & ~(size_t)255;
    return r;
  };
  const size_t MD2 = (size_t)MROWS * D_ * 2;
  const size_t W2  = (size_t)D_ * D_ * 2;

  bf16* xn  = (bf16*)take(MD2);                        // reused as og
  bf16* kT  = (bf16*)take(MD2);
  bf16* vT  = (bf16*)take(MD2);
  char* kshare = take((size_t)BATCH * D_ * D_ * 4);    // k, then kvf
  bf16*  k   = (bf16*)kshare;
  float* kvf = (float*)kshare;
  char* sshare = take((size_t)BATCH * TC * CH * CH * 2); // s, then kvb
  bf16* s   = (bf16*)sshare;
  bf16* kvb = (bf16*)sshare;
  bf16* Wb  = (bf16*)take(W2);
  bf16* og = xn;

  bf16* q = (bf16*)d_out;
  bf16* g = (bf16*)d_out + (size_t)MROWS * D_;

  const int WB = (D_ * D_) / 2048;
  dim3 gp2(D_ / 256, MROWS / 256);  // (8, 32) = 256 blocks, 1/CU

  k_rms<<<MROWS, 256, 0, stream>>>(x, xn);

  k_f2b<<<WB, 256, 0, stream>>>(Wq, Wb);
  k_proj2<1, 1><<<gp2, 512, 0, stream>>>(xn, Wb, q, (bf16*)nullptr);
  k_f2b<<<WB, 256, 0, stream>>>(Wk, Wb);
  k_proj2<1, 3><<<gp2, 512, 0, stream>>>(xn, Wb, k, kT);
  k_f2b<<<WB, 256, 0, stream>>>(Wv, Wb);
  k_proj2<1, 2><<<gp2, 512, 0, stream>>>(xn, Wb, (bf16*)nullptr, vT);
  k_f2b<<<WB, 256, 0, stream>>>(Wg, Wb);
  k_proj2<2, 1><<<gp2, 512, 0, stream>>>(xn, Wb, g, (bf16*)nullptr);

  // intra-chunk: masked scores (lower-tri tiles only) then s @ v
  k_scores<<<dim3(CH / 128, CH / 128, BATCH * TC), 256, 0, stream>>>(q, k, s);
  k_ointra<<<dim3(D_ / 128, CH / 128, BATCH * TC), 256, 0, stream>>>(s, vT, og);

  // k and s are dead now; their memory becomes the KV state
  hipMemsetAsync(kvf, 0, (size_t)BATCH * D_ * D_ * 4, stream);
  hipMemsetAsync(kvb, 0, (size_t)BATCH * D_ * D_ * 2, stream);

  for (int t = 0; t < TC; ++t) {
    k_ointer<<<dim3(D_ / 128, CH / 128, BATCH), 256, 0, stream>>>(
        q, kvb, g, og, t, t ? D_ : 0);
    if (t < TC - 1)
      k_update<<<dim3(D_ / 128, D_ / 128, BATCH), 256, 0, stream>>>(vT, kT, kvf,
                                                                    kvb, t);
  }

  k_f2b<<<WB, 256, 0, stream>>>(Wp, Wb);
  k_final2<<<gp2, 512, 0, stream>>>(og, Wb, out);
}

// Round 9
// 999.132 us; speedup vs baseline: 1.0657x; 1.0657x over previous
//
#include <hip/hip_runtime.h>
#include <hip/hip_bf16.h>

typedef __bf16 bf16;
typedef __bf16 bf16x8 __attribute__((ext_vector_type(8)));
typedef float f32x4 __attribute__((ext_vector_type(4)));
typedef unsigned int u32;

#define D_    2048
#define NSEQ  4096
#define BATCH 2
#define CH    1024   // recurrence chunk (math is chunk-size invariant)
#define TC    4      // chunks per batch
#define MROWS 8192   // BATCH*NSEQ

__device__ __forceinline__ void gload16(const bf16* g, bf16* l) {
  __builtin_amdgcn_global_load_lds(
      (const __attribute__((address_space(1))) u32*)g,
      (__attribute__((address_space(3))) u32*)l, 16, 0, 0);
}

// ================= 128^2 m97-style core (recurrence kernels; unchanged) =====

struct SmemTiles {
  alignas(16) bf16 As[128 * 32];
  alignas(16) bf16 Bs[128 * 32];
};

__device__ __forceinline__ void gemm_core(SmemTiles& sm, const bf16* A, int lda,
                                          const bf16* B, int ldb, int K,
                                          f32x4 acc[4][4]) {
  const int tid = threadIdx.x;
  const int lane = tid & 63;
  const int wave = tid >> 6;
  const int wr = wave >> 1, wc = wave & 1;
  const int l15 = lane & 15, kl = lane >> 4;
  const bf16* Ar = sm.As + (wr * 64 + l15) * 32 + kl * 8;
  const bf16* Br = sm.Bs + (wc * 64 + l15) * 32 + kl * 8;

  for (int k0 = 0; k0 < K; k0 += 32) {
#pragma unroll
    for (int it = 0; it < 2; ++it) {
      int c = it * 256 + tid;
      int r = c >> 2;
      int co = (c & 3) << 3;
      gload16(A + r * lda + k0 + co, sm.As + c * 8);
      gload16(B + r * ldb + k0 + co, sm.Bs + c * 8);
    }
    __syncthreads();
    bf16x8 a[4], b[4];
#pragma unroll
    for (int m = 0; m < 4; ++m) a[m] = *(const bf16x8*)(Ar + m * 16 * 32);
#pragma unroll
    for (int n = 0; n < 4; ++n) b[n] = *(const bf16x8*)(Br + n * 16 * 32);
#pragma unroll
    for (int m = 0; m < 4; ++m)
#pragma unroll
      for (int n = 0; n < 4; ++n)
        acc[m][n] = __builtin_amdgcn_mfma_f32_16x16x32_bf16(a[m], b[n], acc[m][n], 0, 0, 0);
    __syncthreads();
  }
}

#define EPILOGUE_VARS                              \
  const int lane = threadIdx.x & 63;               \
  const int wave = threadIdx.x >> 6;               \
  const int wr = wave >> 1, wc = wave & 1;         \
  const int l15 = lane & 15, kl = lane >> 4;

// ================= 128x256 single-buffer core (2 blocks/CU) =================
//
// Mechanism: m97-style full-drain sync (proven race-free) + cross-block
// overlap (m114). 8 waves (2M x 4N), per-wave C sub-tile 64x64 (acc 4x4 =
// 64 VGPR), LDS = A 128x64 + B 256x64 = 48 KB single-buffered.
// __launch_bounds__(512,4) caps VGPR at 128 -> 2 blocks/CU resident; while
// one block drains its __syncthreads (vmcnt0+lgkm0+barrier), the other's
// waves issue MFMA.
// LDS layout per matrix: slab(rb, ks) holds rows rb*16..+15, cols ks*32..+31;
// lane l owns 16B chunk {row rb*16+(l&15), cols ks*32+(l>>4)*8..+7} at elem
// rb*1024 + ks*512 + l*8 (bank-conflict-free ds_read_b128, measured 0).
// Staging per K-tile: A = 8 slabs x 2 ks -> wave w loads (rb=w, ks=0/1);
// B = 16 slabs x 2 ks -> wave w loads (nb=2w+(j>>1), ks=j&1), j=0..3.

struct SmemHalf {
  alignas(16) bf16 A[128 * 64];   // 8 slabs x 1024
  alignas(16) bf16 B[256 * 64];   // 16 slabs x 1024
};

__device__ __forceinline__ void gemmH_core(SmemHalf& sm, const bf16* A,
                                           int lda, const bf16* B, int ldb,
                                           int K, f32x4 acc[4][4]) {
  const int tid = threadIdx.x;
  const int wave = tid >> 6, lane = tid & 63;
  const int wr = wave >> 2, wc = wave & 3;
  const int r16 = lane & 15, c8 = lane >> 4;
  const int aoff = (wr * 4) * 1024 + lane * 8;
  const int boff = (wc * 4) * 1024 + lane * 8;

  for (int k0 = 0; k0 < K; k0 += 64) {
    // stage A: slab rb = wave, both ks halves (2 loads)
    {
      const bf16* gp = A + (size_t)(wave * 16 + r16) * lda + k0 + c8 * 8;
      bf16* lp = sm.A + wave * 1024 + lane * 8;
      gload16(gp, lp);
      gload16(gp + 32, lp + 512);
    }
    // stage B: 4 loads
#pragma unroll
    for (int j = 0; j < 4; ++j) {
      int nb = 2 * wave + (j >> 1), ks = j & 1;
      gload16(B + (size_t)(nb * 16 + r16) * ldb + k0 + ks * 32 + c8 * 8,
              sm.B + nb * 1024 + ks * 512 + lane * 8);
    }
    __syncthreads();
#pragma unroll
    for (int ks = 0; ks < 2; ++ks) {
      bf16x8 av[4], bv[4];
#pragma unroll
      for (int m = 0; m < 4; ++m)
        av[m] = *(const bf16x8*)&sm.A[aoff + m * 1024 + ks * 512];
#pragma unroll
      for (int n = 0; n < 4; ++n)
        bv[n] = *(const bf16x8*)&sm.B[boff + n * 1024 + ks * 512];
#pragma unroll
      for (int m = 0; m < 4; ++m)
#pragma unroll
        for (int n = 0; n < 4; ++n)
          acc[m][n] = __builtin_amdgcn_mfma_f32_16x16x32_bf16(av[m], bv[n],
                                                              acc[m][n], 0, 0, 0);
    }
    __syncthreads();
  }
}

#define EPILOGUEH_VARS                             \
  const int lane = threadIdx.x & 63;               \
  const int wave = threadIdx.x >> 6;               \
  const int wr = wave >> 2, wc = wave & 3;         \
  const int l15 = lane & 15, kl = lane >> 4;

// ---------------- elementwise kernels ----------------

__global__ __launch_bounds__(256) void k_f2b(const float* __restrict__ in,
                                             bf16* __restrict__ out) {
  int i = (blockIdx.x * 256 + threadIdx.x) * 8;
  float4 a = *(const float4*)(in + i);
  float4 b = *(const float4*)(in + i + 4);
  bf16x8 o;
  o[0] = (bf16)a.x; o[1] = (bf16)a.y; o[2] = (bf16)a.z; o[3] = (bf16)a.w;
  o[4] = (bf16)b.x; o[5] = (bf16)b.y; o[6] = (bf16)b.z; o[7] = (bf16)b.w;
  *(bf16x8*)(out + i) = o;
}

__global__ __launch_bounds__(256) void k_rms(const float* __restrict__ x,
                                             bf16* __restrict__ xn) {
  const int row = blockIdx.x;
  const int tid = threadIdx.x;
  const float* xr = x + (size_t)row * D_;
  float4 a = *(const float4*)(xr + tid * 8);
  float4 b = *(const float4*)(xr + tid * 8 + 4);
  float ss = a.x * a.x + a.y * a.y + a.z * a.z + a.w * a.w +
             b.x * b.x + b.y * b.y + b.z * b.z + b.w * b.w;
#pragma unroll
  for (int o = 32; o > 0; o >>= 1) ss += __shfl_xor(ss, o, 64);
  __shared__ float red[4];
  if ((tid & 63) == 0) red[tid >> 6] = ss;
  __syncthreads();
  float tot = red[0] + red[1] + red[2] + red[3];
  float sc = rsqrtf(tot * (1.f / D_) + 1.1920928955078125e-07f);
  bf16x8 o;
  o[0] = (bf16)(a.x * sc); o[1] = (bf16)(a.y * sc);
  o[2] = (bf16)(a.z * sc); o[3] = (bf16)(a.w * sc);
  o[4] = (bf16)(b.x * sc); o[5] = (bf16)(b.y * sc);
  o[6] = (bf16)(b.z * sc); o[7] = (bf16)(b.w * sc);
  *(bf16x8*)(xn + (size_t)row * D_ + tid * 8) = o;
}

// ---------------- big dense GEMMs on the 128x256 core ----------------
// grid (N/256=8, M/128=64) = 512 blocks -> 2 resident/CU.

// C = act(xn @ W^T); SMODE bit0: store normal, bit1: store transposed [B][D][N]
template <int ACT, int SMODE>
__global__ __launch_bounds__(512, 4) void k_proj2(const bf16* __restrict__ xn,
                                                  const bf16* __restrict__ W,
                                                  bf16* __restrict__ Cn,
                                                  bf16* __restrict__ Ct) {
  __shared__ SmemHalf sm;
  const int row0 = blockIdx.y * 128, col0 = blockIdx.x * 256;
  f32x4 acc[4][4] = {};
  gemmH_core(sm, xn + (size_t)row0 * D_, D_, W + (size_t)col0 * D_, D_, D_, acc);
  EPILOGUEH_VARS
#pragma unroll
  for (int m = 0; m < 4; ++m)
#pragma unroll
    for (int n = 0; n < 4; ++n)
#pragma unroll
      for (int j = 0; j < 4; ++j) {
        int r = row0 + wr * 64 + m * 16 + kl * 4 + j;
        int c = col0 + wc * 64 + n * 16 + l15;
        float v = acc[m][n][j];
        if (ACT == 1) v = v / (1.f + __expf(-v));        // silu
        if (ACT == 2) v = 1.f / (1.f + __expf(-v));      // sigmoid
        bf16 ob = (bf16)v;
        if (SMODE & 1) Cn[(size_t)r * D_ + c] = ob;
        if (SMODE & 2)
          Ct[((size_t)(r >> 12) * D_ + c) * NSEQ + (r & (NSEQ - 1))] = ob;
      }
}

// out = og @ Wp^T (fp32 store)
__global__ __launch_bounds__(512, 4) void k_final2(const bf16* __restrict__ og,
                                                   const bf16* __restrict__ Wp,
                                                   float* __restrict__ out) {
  __shared__ SmemHalf sm;
  const int row0 = blockIdx.y * 128, col0 = blockIdx.x * 256;
  f32x4 acc[4][4] = {};
  gemmH_core(sm, og + (size_t)row0 * D_, D_, Wp + (size_t)col0 * D_, D_, D_, acc);
  EPILOGUEH_VARS
#pragma unroll
  for (int m = 0; m < 4; ++m)
#pragma unroll
    for (int n = 0; n < 4; ++n)
#pragma unroll
      for (int j = 0; j < 4; ++j) {
        int r = row0 + wr * 64 + m * 16 + kl * 4 + j;
        int c = col0 + wc * 64 + n * 16 + l15;
        out[(size_t)r * D_ + c] = acc[m][n][j];
      }
}

// ---------------- chunked-recurrence kernels (128^2 core, unchanged) --------

// s[z] = tril(q_t k_t^T), z = b*TC + t, chunk CH=1024.
__global__ __launch_bounds__(256) void k_scores(const bf16* __restrict__ q,
                                                const bf16* __restrict__ k,
                                                bf16* __restrict__ s) {
  const int z = blockIdx.z, b = z >> 2, t = z & 3;
  const int row0 = blockIdx.y * 128, col0 = blockIdx.x * 128;
  if (col0 > row0) return;  // strictly upper tile
  __shared__ SmemTiles sm;
  f32x4 acc[4][4] = {};
  gemm_core(sm, q + (size_t)(b * NSEQ + t * CH + row0) * D_, D_,
                k + (size_t)(b * NSEQ + t * CH + col0) * D_, D_, D_, acc);
  EPILOGUE_VARS
  bf16* sp = s + (size_t)z * CH * CH;
#pragma unroll
  for (int m = 0; m < 4; ++m)
#pragma unroll
    for (int n = 0; n < 4; ++n)
#pragma unroll
      for (int j = 0; j < 4; ++j) {
        int i = row0 + wr * 64 + m * 16 + kl * 4 + j;
        int jc = col0 + wc * 64 + n * 16 + l15;
        float v = (i >= jc) ? acc[m][n][j] : 0.f;
        sp[(size_t)i * CH + jc] = (bf16)v;
      }
}

// og[chunk rows] = s @ v  (intra-chunk; K trimmed to lower-tri extent)
__global__ __launch_bounds__(256) void k_ointra(const bf16* __restrict__ s,
                                                const bf16* __restrict__ vT,
                                                bf16* __restrict__ og) {
  __shared__ SmemTiles sm;
  const int z = blockIdx.z, b = z >> 2, t = z & 3;
  const int row0 = blockIdx.y * 128, col0 = blockIdx.x * 128;
  const int K = row0 + 128;
  f32x4 acc[4][4] = {};
  gemm_core(sm, s + (size_t)z * CH * CH + (size_t)row0 * CH, CH,
                vT + (size_t)b * D_ * NSEQ + (size_t)col0 * NSEQ + t * CH, NSEQ,
                K, acc);
  EPILOGUE_VARS
#pragma unroll
  for (int m = 0; m < 4; ++m)
#pragma unroll
    for (int n = 0; n < 4; ++n)
#pragma unroll
      for (int j = 0; j < 4; ++j) {
        int i = row0 + wr * 64 + m * 16 + kl * 4 + j;
        int c = col0 + wc * 64 + n * 16 + l15;
        og[(size_t)(b * NSEQ + t * CH + i) * D_ + c] = (bf16)acc[m][n][j];
      }
}

// og = (og + q_t @ kvT^T) * g   (Kin==0 for t==0: just gate)
__global__ __launch_bounds__(256) void k_ointer(const bf16* __restrict__ q,
                                                const bf16* __restrict__ kvb,
                                                const bf16* __restrict__ g,
                                                bf16* __restrict__ og, int t,
                                                int Kin) {
  __shared__ SmemTiles sm;
  const int b = blockIdx.z;
  const int row0 = blockIdx.y * 128, col0 = blockIdx.x * 128;
  f32x4 acc[4][4] = {};
  gemm_core(sm, q + (size_t)(b * NSEQ + t * CH + row0) * D_, D_,
                kvb + (size_t)b * D_ * D_ + (size_t)col0 * D_, D_, Kin, acc);
  EPILOGUE_VARS
#pragma unroll
  for (int m = 0; m < 4; ++m)
#pragma unroll
    for (int n = 0; n < 4; ++n)
#pragma unroll
      for (int j = 0; j < 4; ++j) {
        int i = row0 + wr * 64 + m * 16 + kl * 4 + j;
        int c = col0 + wc * 64 + n * 16 + l15;
        size_t idx = (size_t)(b * NSEQ + t * CH + i) * D_ + c;
        float v = ((float)og[idx] + acc[m][n][j]) * (float)g[idx];
        og[idx] = (bf16)v;
      }
}

// kvT[b][e][d] += sum_{j in chunk t} v[j][e] k[j][d]
__global__ __launch_bounds__(256) void k_update(const bf16* __restrict__ vT,
                                                const bf16* __restrict__ kT,
                                                float* __restrict__ kvf,
                                                bf16* __restrict__ kvb, int t) {
  __shared__ SmemTiles sm;
  const int b = blockIdx.z;
  const int row0 = blockIdx.y * 128, col0 = blockIdx.x * 128;
  f32x4 acc[4][4] = {};
  gemm_core(sm, vT + (size_t)b * D_ * NSEQ + (size_t)row0 * NSEQ + t * CH, NSEQ,
                kT + (size_t)b * D_ * NSEQ + (size_t)col0 * NSEQ + t * CH, NSEQ,
                CH, acc);
  EPILOGUE_VARS
#pragma unroll
  for (int m = 0; m < 4; ++m)
#pragma unroll
    for (int n = 0; n < 4; ++n)
#pragma unroll
      for (int j = 0; j < 4; ++j) {
        int e = row0 + wr * 64 + m * 16 + kl * 4 + j;
        int d = col0 + wc * 64 + n * 16 + l15;
        size_t idx = (size_t)b * D_ * D_ + (size_t)e * D_ + d;
        float v = kvf[idx] + acc[m][n][j];
        kvf[idx] = v;
        kvb[idx] = (bf16)v;
      }
}

// ---------------- host launch ----------------
//
// Workspace plan (153 MiB): xn/og 32 | kT 32 | vT 32 | {k->kvf} 32 |
// {s->kvb} 16.78 | Wb 8.  q,g live in d_out (dead before k_final2).

extern "C" void kernel_launch(void* const* d_in, const int* in_sizes, int n_in,
                              void* d_out, int out_size, void* d_ws, size_t ws_size,
                              hipStream_t stream) {
  (void)in_sizes; (void)n_in; (void)out_size; (void)ws_size;
  const float* x  = (const float*)d_in[0];
  const float* Wq = (const float*)d_in[1];
  const float* Wk = (const float*)d_in[2];
  const float* Wv = (const float*)d_in[3];
  const float* Wg = (const float*)d_in[4];
  const float* Wp = (const float*)d_in[5];
  float* out = (float*)d_out;

  char* p = (char*)d_ws;
  auto take = [&](size_t bytes) {
    char* r = p;
    p += (bytes + 255) & ~(size_t)255;
    return r;
  };
  const size_t MD2 = (size_t)MROWS * D_ * 2;
  const size_t W2  = (size_t)D_ * D_ * 2;

  bf16* xn  = (bf16*)take(MD2);                        // reused as og
  bf16* kT  = (bf16*)take(MD2);
  bf16* vT  = (bf16*)take(MD2);
  char* kshare = take((size_t)BATCH * D_ * D_ * 4);    // k, then kvf
  bf16*  k   = (bf16*)kshare;
  float* kvf = (float*)kshare;
  char* sshare = take((size_t)BATCH * TC * CH * CH * 2); // s, then kvb
  bf16* s   = (bf16*)sshare;
  bf16* kvb = (bf16*)sshare;
  bf16* Wb  = (bf16*)take(W2);
  bf16* og = xn;

  bf16* q = (bf16*)d_out;
  bf16* g = (bf16*)d_out + (size_t)MROWS * D_;

  const int WB = (D_ * D_) / 2048;
  dim3 gpH(D_ / 256, MROWS / 128);  // (8, 64) = 512 blocks, 2/CU

  k_rms<<<MROWS, 256, 0, stream>>>(x, xn);

  k_f2b<<<WB, 256, 0, stream>>>(Wq, Wb);
  k_proj2<1, 1><<<gpH, 512, 0, stream>>>(xn, Wb, q, (bf16*)nullptr);
  k_f2b<<<WB, 256, 0, stream>>>(Wk, Wb);
  k_proj2<1, 3><<<gpH, 512, 0, stream>>>(xn, Wb, k, kT);
  k_f2b<<<WB, 256, 0, stream>>>(Wv, Wb);
  k_proj2<1, 2><<<gpH, 512, 0, stream>>>(xn, Wb, (bf16*)nullptr, vT);
  k_f2b<<<WB, 256, 0, stream>>>(Wg, Wb);
  k_proj2<2, 1><<<gpH, 512, 0, stream>>>(xn, Wb, g, (bf16*)nullptr);

  // intra-chunk: masked scores (lower-tri tiles only) then s @ v
  k_scores<<<dim3(CH / 128, CH / 128, BATCH * TC), 256, 0, stream>>>(q, k, s);
  k_ointra<<<dim3(D_ / 128, CH / 128, BATCH * TC), 256, 0, stream>>>(s, vT, og);

  // k and s are dead now; their memory becomes the KV state
  hipMemsetAsync(kvf, 0, (size_t)BATCH * D_ * D_ * 4, stream);
  hipMemsetAsync(kvb, 0, (size_t)BATCH * D_ * D_ * 2, stream);

  for (int t = 0; t < TC; ++t) {
    k_ointer<<<dim3(D_ / 128, CH / 128, BATCH), 256, 0, stream>>>(
        q, kvb, g, og, t, t ? D_ : 0);
    if (t < TC - 1)
      k_update<<<dim3(D_ / 128, D_ / 128, BATCH), 256, 0, stream>>>(vT, kT, kvf,
                                                                    kvb, t);
  }

  k_f2b<<<WB, 256, 0, stream>>>(Wp, Wb);
  k_final2<<<gpH, 512, 0, stream>>>(og, Wb, out);
}

// Round 10
// 963.922 us; speedup vs baseline: 1.1047x; 1.0365x over previous
//
#include <hip/hip_runtime.h>
#include <hip/hip_bf16.h>

typedef __bf16 bf16;
typedef __bf16 bf16x8 __attribute__((ext_vector_type(8)));
typedef float f32x4 __attribute__((ext_vector_type(4)));
typedef unsigned int u32;

#define D_    2048
#define NSEQ  4096
#define BATCH 2
#define CH    1024   // recurrence chunk (math is chunk-size invariant)
#define TC    4      // chunks per batch
#define MROWS 8192   // BATCH*NSEQ

__device__ __forceinline__ void gload16(const bf16* g, bf16* l) {
  __builtin_amdgcn_global_load_lds(
      (const __attribute__((address_space(1))) u32*)g,
      (__attribute__((address_space(3))) u32*)l, 16, 0, 0);
}

// ============ 128^2 core, minimal 2-phase (T3-min, m248 recipe) ============
//
// stage(t+1 -> other buffer) issued BEFORE compute(t); ONE __syncthreads per
// K-step (its implicit vmcnt(0)+lgkmcnt(0) drain is the buffer handoff).
// Race-free by construction: reads of buf[t&1] precede the barrier (lgkm
// drained there); stage of buf[(t+1)&1] lands before the barrier's vmcnt(0);
// nobody touches a buffer being written.

struct SmemTiles {
  alignas(16) bf16 As[2][128 * 32];
  alignas(16) bf16 Bs[2][128 * 32];
};

__device__ __forceinline__ void stage128(SmemTiles& sm, int bb, const bf16* A,
                                         int lda, const bf16* B, int ldb,
                                         int k0, int tid) {
#pragma unroll
  for (int it = 0; it < 2; ++it) {
    int c = it * 256 + tid;      // 16B chunk index, 512 chunks per tile
    int r = c >> 2;              // 4 chunks per 32-elem row
    int co = (c & 3) << 3;
    gload16(A + (size_t)r * lda + k0 + co, &sm.As[bb][c * 8]);
    gload16(B + (size_t)r * ldb + k0 + co, &sm.Bs[bb][c * 8]);
  }
}

__device__ __forceinline__ void gemm_core(SmemTiles& sm, const bf16* A, int lda,
                                          const bf16* B, int ldb, int K,
                                          f32x4 acc[4][4]) {
  const int tid = threadIdx.x;
  const int lane = tid & 63;
  const int wave = tid >> 6;
  const int wr = wave >> 1, wc = wave & 1;
  const int l15 = lane & 15, kl = lane >> 4;
  const int NT = K >> 5;
  if (NT <= 0) return;

  stage128(sm, 0, A, lda, B, ldb, 0, tid);
  __syncthreads();

  const int ao = (wr * 64 + l15) * 32 + kl * 8;
  const int bo = (wc * 64 + l15) * 32 + kl * 8;

  for (int t = 0; t < NT; ++t) {
    if (t + 1 < NT)
      stage128(sm, (t + 1) & 1, A, lda, B, ldb, (t + 1) * 32, tid);
    const bf16* Ab = sm.As[t & 1];
    const bf16* Bb = sm.Bs[t & 1];
    bf16x8 a[4], b[4];
#pragma unroll
    for (int m = 0; m < 4; ++m) a[m] = *(const bf16x8*)(Ab + ao + m * 16 * 32);
#pragma unroll
    for (int n = 0; n < 4; ++n) b[n] = *(const bf16x8*)(Bb + bo + n * 16 * 32);
    __builtin_amdgcn_s_setprio(1);
#pragma unroll
    for (int m = 0; m < 4; ++m)
#pragma unroll
      for (int n = 0; n < 4; ++n)
        acc[m][n] = __builtin_amdgcn_mfma_f32_16x16x32_bf16(a[m], b[n], acc[m][n], 0, 0, 0);
    __builtin_amdgcn_s_setprio(0);
    if (t + 1 < NT) __syncthreads();
  }
}

#define EPILOGUE_VARS                              \
  const int lane = threadIdx.x & 63;               \
  const int wave = threadIdx.x >> 6;               \
  const int wr = wave >> 1, wc = wave & 1;         \
  const int l15 = lane & 15, kl = lane >> 4;

// ============ 256^2 core, minimal 2-phase (8 waves, 8x4 frags) =============
//
// Same handoff discipline as gemm_core. LDS layout per buffer/matrix:
// slab(mb,ks) holds rows mb*16..+15, cols ks*32..+31; lane l owns the 16B
// chunk {row mb*16+(l&15), cols ks*32+(l>>4)*8..+7} at elem
// mb*1024 + ks*512 + l*8 -> every ds_read_b128 is 64 lanes x consecutive
// 16B (bank-conflict-free, measured 0 in rounds 6/8/9).

struct Smem256 {
  alignas(16) bf16 A[2][256 * 64];
  alignas(16) bf16 B[2][256 * 64];
};

__device__ __forceinline__ void stage256(Smem256& sm, int bb, const bf16* A,
                                         int lda, const bf16* B, int ldb,
                                         int k0, int wave, int lane) {
  const int r16 = lane & 15, c8 = lane >> 4;
#pragma unroll
  for (int s = 0; s < 4; ++s) {
    int mb = 2 * wave + (s >> 1), ks = s & 1;
    gload16(A + (size_t)(mb * 16 + r16) * lda + k0 + ks * 32 + c8 * 8,
            &sm.A[bb][mb * 1024 + ks * 512 + lane * 8]);
  }
#pragma unroll
  for (int s = 0; s < 4; ++s) {
    int mb = 2 * wave + (s >> 1), ks = s & 1;
    gload16(B + (size_t)(mb * 16 + r16) * ldb + k0 + ks * 32 + c8 * 8,
            &sm.B[bb][mb * 1024 + ks * 512 + lane * 8]);
  }
}

__device__ __forceinline__ void gemm256_core(Smem256& sm, const bf16* A,
                                             int lda, const bf16* B, int ldb,
                                             int K, f32x4 acc[8][4]) {
  const int tid = threadIdx.x;
  const int wave = tid >> 6, lane = tid & 63;
  const int wr = wave >> 2, wc = wave & 3;
  const int NT = K >> 6;
  if (NT <= 0) return;

  stage256(sm, 0, A, lda, B, ldb, 0, wave, lane);
  __syncthreads();

  const int aoff = wr * 8192 + lane * 8;  // wave's A half (8 slabs)
  const int boff = wc * 4096 + lane * 8;  // wave's B quarter (4 slabs)

  for (int t = 0; t < NT; ++t) {
    if (t + 1 < NT)
      stage256(sm, (t + 1) & 1, A, lda, B, ldb, (t + 1) * 64, wave, lane);
    const bf16* Ab = sm.A[t & 1];
    const bf16* Bb = sm.B[t & 1];
#pragma unroll
    for (int ks = 0; ks < 2; ++ks) {
      bf16x8 av[8], bv[4];
#pragma unroll
      for (int mf = 0; mf < 8; ++mf)
        av[mf] = *(const bf16x8*)&Ab[aoff + mf * 1024 + ks * 512];
#pragma unroll
      for (int nf = 0; nf < 4; ++nf)
        bv[nf] = *(const bf16x8*)&Bb[boff + nf * 1024 + ks * 512];
      __builtin_amdgcn_s_setprio(1);
#pragma unroll
      for (int mf = 0; mf < 8; ++mf)
#pragma unroll
        for (int nf = 0; nf < 4; ++nf)
          acc[mf][nf] = __builtin_amdgcn_mfma_f32_16x16x32_bf16(av[mf], bv[nf],
                                                                acc[mf][nf], 0, 0, 0);
      __builtin_amdgcn_s_setprio(0);
    }
    if (t + 1 < NT) __syncthreads();
  }
}

#define EPILOGUE256_VARS                           \
  const int lane = threadIdx.x & 63;               \
  const int wave = threadIdx.x >> 6;               \
  const int wr = wave >> 2, wc = wave & 3;         \
  const int l15 = lane & 15, kl = lane >> 4;

// ---------------- elementwise kernels ----------------

__global__ __launch_bounds__(256) void k_f2b(const float* __restrict__ in,
                                             bf16* __restrict__ out) {
  int i = (blockIdx.x * 256 + threadIdx.x) * 8;
  float4 a = *(const float4*)(in + i);
  float4 b = *(const float4*)(in + i + 4);
  bf16x8 o;
  o[0] = (bf16)a.x; o[1] = (bf16)a.y; o[2] = (bf16)a.z; o[3] = (bf16)a.w;
  o[4] = (bf16)b.x; o[5] = (bf16)b.y; o[6] = (bf16)b.z; o[7] = (bf16)b.w;
  *(bf16x8*)(out + i) = o;
}

__global__ __launch_bounds__(256) void k_rms(const float* __restrict__ x,
                                             bf16* __restrict__ xn) {
  const int row = blockIdx.x;
  const int tid = threadIdx.x;
  const float* xr = x + (size_t)row * D_;
  float4 a = *(const float4*)(xr + tid * 8);
  float4 b = *(const float4*)(xr + tid * 8 + 4);
  float ss = a.x * a.x + a.y * a.y + a.z * a.z + a.w * a.w +
             b.x * b.x + b.y * b.y + b.z * b.z + b.w * b.w;
#pragma unroll
  for (int o = 32; o > 0; o >>= 1) ss += __shfl_xor(ss, o, 64);
  __shared__ float red[4];
  if ((tid & 63) == 0) red[tid >> 6] = ss;
  __syncthreads();
  float tot = red[0] + red[1] + red[2] + red[3];
  float sc = rsqrtf(tot * (1.f / D_) + 1.1920928955078125e-07f);
  bf16x8 o;
  o[0] = (bf16)(a.x * sc); o[1] = (bf16)(a.y * sc);
  o[2] = (bf16)(a.z * sc); o[3] = (bf16)(a.w * sc);
  o[4] = (bf16)(b.x * sc); o[5] = (bf16)(b.y * sc);
  o[6] = (bf16)(b.z * sc); o[7] = (bf16)(b.w * sc);
  *(bf16x8*)(xn + (size_t)row * D_ + tid * 8) = o;
}

// ---------------- big dense GEMMs (256^2 2-phase core) ----------------
// grid (N/256=8, M/256=32) = 256 blocks -> 1 block/CU.

// C = act(xn @ W^T); SMODE bit0: store normal, bit1: store transposed [B][D][N]
template <int ACT, int SMODE>
__global__ __launch_bounds__(512, 2) void k_proj2(const bf16* __restrict__ xn,
                                                  const bf16* __restrict__ W,
                                                  bf16* __restrict__ Cn,
                                                  bf16* __restrict__ Ct) {
  __shared__ Smem256 sm;
  const int row0 = blockIdx.y * 256, col0 = blockIdx.x * 256;
  f32x4 acc[8][4] = {};
  gemm256_core(sm, xn + (size_t)row0 * D_, D_, W + (size_t)col0 * D_, D_, D_, acc);
  EPILOGUE256_VARS
#pragma unroll
  for (int mf = 0; mf < 8; ++mf)
#pragma unroll
    for (int nf = 0; nf < 4; ++nf)
#pragma unroll
      for (int j = 0; j < 4; ++j) {
        int r = row0 + wr * 128 + mf * 16 + kl * 4 + j;
        int c = col0 + wc * 64 + nf * 16 + l15;
        float v = acc[mf][nf][j];
        if (ACT == 1) v = v / (1.f + __expf(-v));        // silu
        if (ACT == 2) v = 1.f / (1.f + __expf(-v));      // sigmoid
        bf16 ob = (bf16)v;
        if (SMODE & 1) Cn[(size_t)r * D_ + c] = ob;
        if (SMODE & 2)
          Ct[((size_t)(r >> 12) * D_ + c) * NSEQ + (r & (NSEQ - 1))] = ob;
      }
}

// out = og @ Wp^T (fp32 store)
__global__ __launch_bounds__(512, 2) void k_final2(const bf16* __restrict__ og,
                                                   const bf16* __restrict__ Wp,
                                                   float* __restrict__ out) {
  __shared__ Smem256 sm;
  const int row0 = blockIdx.y * 256, col0 = blockIdx.x * 256;
  f32x4 acc[8][4] = {};
  gemm256_core(sm, og + (size_t)row0 * D_, D_, Wp + (size_t)col0 * D_, D_, D_, acc);
  EPILOGUE256_VARS
#pragma unroll
  for (int mf = 0; mf < 8; ++mf)
#pragma unroll
    for (int nf = 0; nf < 4; ++nf)
#pragma unroll
      for (int j = 0; j < 4; ++j) {
        int r = row0 + wr * 128 + mf * 16 + kl * 4 + j;
        int c = col0 + wc * 64 + nf * 16 + l15;
        out[(size_t)r * D_ + c] = acc[mf][nf][j];
      }
}

// ---------------- chunked-recurrence kernels (128^2 2-phase core) -----------

// s[z] = tril(q_t k_t^T), z = b*TC + t, chunk CH=1024.
__global__ __launch_bounds__(256) void k_scores(const bf16* __restrict__ q,
                                                const bf16* __restrict__ k,
                                                bf16* __restrict__ s) {
  const int z = blockIdx.z, b = z >> 2, t = z & 3;
  const int row0 = blockIdx.y * 128, col0 = blockIdx.x * 128;
  if (col0 > row0) return;  // strictly upper tile
  __shared__ SmemTiles sm;
  f32x4 acc[4][4] = {};
  gemm_core(sm, q + (size_t)(b * NSEQ + t * CH + row0) * D_, D_,
                k + (size_t)(b * NSEQ + t * CH + col0) * D_, D_, D_, acc);
  EPILOGUE_VARS
  bf16* sp = s + (size_t)z * CH * CH;
#pragma unroll
  for (int m = 0; m < 4; ++m)
#pragma unroll
    for (int n = 0; n < 4; ++n)
#pragma unroll
      for (int j = 0; j < 4; ++j) {
        int i = row0 + wr * 64 + m * 16 + kl * 4 + j;
        int jc = col0 + wc * 64 + n * 16 + l15;
        float v = (i >= jc) ? acc[m][n][j] : 0.f;
        sp[(size_t)i * CH + jc] = (bf16)v;
      }
}

// og[chunk rows] = s @ v  (intra-chunk; K trimmed to lower-tri extent)
__global__ __launch_bounds__(256) void k_ointra(const bf16* __restrict__ s,
                                                const bf16* __restrict__ vT,
                                                bf16* __restrict__ og) {
  __shared__ SmemTiles sm;
  const int z = blockIdx.z, b = z >> 2, t = z & 3;
  const int row0 = blockIdx.y * 128, col0 = blockIdx.x * 128;
  const int K = row0 + 128;
  f32x4 acc[4][4] = {};
  gemm_core(sm, s + (size_t)z * CH * CH + (size_t)row0 * CH, CH,
                vT + (size_t)b * D_ * NSEQ + (size_t)col0 * NSEQ + t * CH, NSEQ,
                K, acc);
  EPILOGUE_VARS
#pragma unroll
  for (int m = 0; m < 4; ++m)
#pragma unroll
    for (int n = 0; n < 4; ++n)
#pragma unroll
      for (int j = 0; j < 4; ++j) {
        int i = row0 + wr * 64 + m * 16 + kl * 4 + j;
        int c = col0 + wc * 64 + n * 16 + l15;
        og[(size_t)(b * NSEQ + t * CH + i) * D_ + c] = (bf16)acc[m][n][j];
      }
}

// og = (og + q_t @ kvT^T) * g   (Kin==0 for t==0: just gate)
__global__ __launch_bounds__(256) void k_ointer(const bf16* __restrict__ q,
                                                const bf16* __restrict__ kvb,
                                                const bf16* __restrict__ g,
                                                bf16* __restrict__ og, int t,
                                                int Kin) {
  __shared__ SmemTiles sm;
  const int b = blockIdx.z;
  const int row0 = blockIdx.y * 128, col0 = blockIdx.x * 128;
  f32x4 acc[4][4] = {};
  gemm_core(sm, q + (size_t)(b * NSEQ + t * CH + row0) * D_, D_,
                kvb + (size_t)b * D_ * D_ + (size_t)col0 * D_, D_, Kin, acc);
  EPILOGUE_VARS
#pragma unroll
  for (int m = 0; m < 4; ++m)
#pragma unroll
    for (int n = 0; n < 4; ++n)
#pragma unroll
      for (int j = 0; j < 4; ++j) {
        int i = row0 + wr * 64 + m * 16 + kl * 4 + j;
        int c = col0 + wc * 64 + n * 16 + l15;
        size_t idx = (size_t)(b * NSEQ + t * CH + i) * D_ + c;
        float v = ((float)og[idx] + acc[m][n][j]) * (float)g[idx];
        og[idx] = (bf16)v;
      }
}

// kvT[b][e][d] += sum_{j in chunk t} v[j][e] k[j][d]
__global__ __launch_bounds__(256) void k_update(const bf16* __restrict__ vT,
                                                const bf16* __restrict__ kT,
                                                float* __restrict__ kvf,
                                                bf16* __restrict__ kvb, int t) {
  __shared__ SmemTiles sm;
  const int b = blockIdx.z;
  const int row0 = blockIdx.y * 128, col0 = blockIdx.x * 128;
  f32x4 acc[4][4] = {};
  gemm_core(sm, vT + (size_t)b * D_ * NSEQ + (size_t)row0 * NSEQ + t * CH, NSEQ,
                kT + (size_t)b * D_ * NSEQ + (size_t)col0 * NSEQ + t * CH, NSEQ,
                CH, acc);
  EPILOGUE_VARS
#pragma unroll
  for (int m = 0; m < 4; ++m)
#pragma unroll
    for (int n = 0; n < 4; ++n)
#pragma unroll
      for (int j = 0; j < 4; ++j) {
        int e = row0 + wr * 64 + m * 16 + kl * 4 + j;
        int d = col0 + wc * 64 + n * 16 + l15;
        size_t idx = (size_t)b * D_ * D_ + (size_t)e * D_ + d;
        float v = kvf[idx] + acc[m][n][j];
        kvf[idx] = v;
        kvb[idx] = (bf16)v;
      }
}

// ---------------- host launch ----------------
//
// Workspace plan (153 MiB): xn/og 32 | kT 32 | vT 32 | {k->kvf} 32 |
// {s->kvb} 16.78 | Wb 8.  q,g live in d_out (dead before k_final2).

extern "C" void kernel_launch(void* const* d_in, const int* in_sizes, int n_in,
                              void* d_out, int out_size, void* d_ws, size_t ws_size,
                              hipStream_t stream) {
  (void)in_sizes; (void)n_in; (void)out_size; (void)ws_size;
  const float* x  = (const float*)d_in[0];
  const float* Wq = (const float*)d_in[1];
  const float* Wk = (const float*)d_in[2];
  const float* Wv = (const float*)d_in[3];
  const float* Wg = (const float*)d_in[4];
  const float* Wp = (const float*)d_in[5];
  float* out = (float*)d_out;

  char* p = (char*)d_ws;
  auto take = [&](size_t bytes) {
    char* r = p;
    p += (bytes + 255) & ~(size_t)255;
    return r;
  };
  const size_t MD2 = (size_t)MROWS * D_ * 2;
  const size_t W2  = (size_t)D_ * D_ * 2;

  bf16* xn  = (bf16*)take(MD2);                        // reused as og
  bf16* kT  = (bf16*)take(MD2);
  bf16* vT  = (bf16*)take(MD2);
  char* kshare = take((size_t)BATCH * D_ * D_ * 4);    // k, then kvf
  bf16*  k   = (bf16*)kshare;
  float* kvf = (float*)kshare;
  char* sshare = take((size_t)BATCH * TC * CH * CH * 2); // s, then kvb
  bf16* s   = (bf16*)sshare;
  bf16* kvb = (bf16*)sshare;
  bf16* Wb  = (bf16*)take(W2);
  bf16* og = xn;

  bf16* q = (bf16*)d_out;
  bf16* g = (bf16*)d_out + (size_t)MROWS * D_;

  const int WB = (D_ * D_) / 2048;
  dim3 gp2(D_ / 256, MROWS / 256);  // (8, 32) = 256 blocks, 1/CU

  k_rms<<<MROWS, 256, 0, stream>>>(x, xn);

  k_f2b<<<WB, 256, 0, stream>>>(Wq, Wb);
  k_proj2<1, 1><<<gp2, 512, 0, stream>>>(xn, Wb, q, (bf16*)nullptr);
  k_f2b<<<WB, 256, 0, stream>>>(Wk, Wb);
  k_proj2<1, 3><<<gp2, 512, 0, stream>>>(xn, Wb, k, kT);
  k_f2b<<<WB, 256, 0, stream>>>(Wv, Wb);
  k_proj2<1, 2><<<gp2, 512, 0, stream>>>(xn, Wb, (bf16*)nullptr, vT);
  k_f2b<<<WB, 256, 0, stream>>>(Wg, Wb);
  k_proj2<2, 1><<<gp2, 512, 0, stream>>>(xn, Wb, g, (bf16*)nullptr);

  // intra-chunk: masked scores (lower-tri tiles only) then s @ v
  k_scores<<<dim3(CH / 128, CH / 128, BATCH * TC), 256, 0, stream>>>(q, k, s);
  k_ointra<<<dim3(D_ / 128, CH / 128, BATCH * TC), 256, 0, stream>>>(s, vT, og);

  // k and s are dead now; their memory becomes the KV state
  hipMemsetAsync(kvf, 0, (size_t)BATCH * D_ * D_ * 4, stream);
  hipMemsetAsync(kvb, 0, (size_t)BATCH * D_ * D_ * 2, stream);

  for (int t = 0; t < TC; ++t) {
    k_ointer<<<dim3(D_ / 128, CH / 128, BATCH), 256, 0, stream>>>(
        q, kvb, g, og, t, t ? D_ : 0);
    if (t < TC - 1)
      k_update<<<dim3(D_ / 128, D_ / 128, BATCH), 256, 0, stream>>>(vT, kT, kvf,
                                                                    kvb, t);
  }

  k_f2b<<<WB, 256, 0, stream>>>(Wp, Wb);
  k_final2<<<gp2, 512, 0, stream>>>(og, Wb, out);
}

// Round 11
// 872.392 us; speedup vs baseline: 1.2206x; 1.1049x over previous
//
#include <hip/hip_runtime.h>
#include <hip/hip_bf16.h>

typedef __bf16 bf16;
typedef __bf16 bf16x8 __attribute__((ext_vector_type(8)));
typedef float f32x4 __attribute__((ext_vector_type(4)));
typedef unsigned int u32;

#define D_    2048
#define NSEQ  4096
#define BATCH 2
#define CH    1024   // recurrence chunk (math is chunk-size invariant)
#define TC    4      // chunks per batch
#define MROWS 8192   // BATCH*NSEQ

__device__ __forceinline__ void gload16(const bf16* g, bf16* l) {
  __builtin_amdgcn_global_load_lds(
      (const __attribute__((address_space(1))) u32*)g,
      (__attribute__((address_space(3))) u32*)l, 16, 0, 0);
}

// ============ 128^2 core, minimal 2-phase (recurrence kernels; proven) ======

struct SmemTiles {
  alignas(16) bf16 As[2][128 * 32];
  alignas(16) bf16 Bs[2][128 * 32];
};

__device__ __forceinline__ void stage128(SmemTiles& sm, int bb, const bf16* A,
                                         int lda, const bf16* B, int ldb,
                                         int k0, int tid) {
#pragma unroll
  for (int it = 0; it < 2; ++it) {
    int c = it * 256 + tid;      // 16B chunk index, 512 chunks per tile
    int r = c >> 2;              // 4 chunks per 32-elem row
    int co = (c & 3) << 3;
    gload16(A + (size_t)r * lda + k0 + co, &sm.As[bb][c * 8]);
    gload16(B + (size_t)r * ldb + k0 + co, &sm.Bs[bb][c * 8]);
  }
}

__device__ __forceinline__ void gemm_core(SmemTiles& sm, const bf16* A, int lda,
                                          const bf16* B, int ldb, int K,
                                          f32x4 acc[4][4]) {
  const int tid = threadIdx.x;
  const int lane = tid & 63;
  const int wave = tid >> 6;
  const int wr = wave >> 1, wc = wave & 1;
  const int l15 = lane & 15, kl = lane >> 4;
  const int NT = K >> 5;
  if (NT <= 0) return;

  stage128(sm, 0, A, lda, B, ldb, 0, tid);
  __syncthreads();

  const int ao = (wr * 64 + l15) * 32 + kl * 8;
  const int bo = (wc * 64 + l15) * 32 + kl * 8;

  for (int t = 0; t < NT; ++t) {
    if (t + 1 < NT)
      stage128(sm, (t + 1) & 1, A, lda, B, ldb, (t + 1) * 32, tid);
    const bf16* Ab = sm.As[t & 1];
    const bf16* Bb = sm.Bs[t & 1];
    bf16x8 a[4], b[4];
#pragma unroll
    for (int m = 0; m < 4; ++m) a[m] = *(const bf16x8*)(Ab + ao + m * 16 * 32);
#pragma unroll
    for (int n = 0; n < 4; ++n) b[n] = *(const bf16x8*)(Bb + bo + n * 16 * 32);
    __builtin_amdgcn_s_setprio(1);
#pragma unroll
    for (int m = 0; m < 4; ++m)
#pragma unroll
      for (int n = 0; n < 4; ++n)
        acc[m][n] = __builtin_amdgcn_mfma_f32_16x16x32_bf16(a[m], b[n], acc[m][n], 0, 0, 0);
    __builtin_amdgcn_s_setprio(0);
    if (t + 1 < NT) __syncthreads();
  }
}

#define EPILOGUE_VARS                              \
  const int lane = threadIdx.x & 63;               \
  const int wave = threadIdx.x >> 6;               \
  const int wr = wave >> 1, wc = wave & 1;         \
  const int l15 = lane & 15, kl = lane >> 4;

// ============ 128x256 big-GEMM core: counted-vmcnt 2-deep + 2 blocks/CU =====
//
// Combines the two individually-proven mechanisms:
//  - R6's counted-vmcnt pipeline (loads stay in flight across barriers;
//    never a full drain in the main loop)
//  - 2 resident blocks/CU (48 KB LDS, <=128 VGPR): block B's MFMA covers
//    block A's barrier/wait stall (m114 cross-block overlap).
// 8 waves (2M x 4N), per-wave C 64x64 (acc 4x4 = 64 VGPR), BK=32.
// LDS slabs: slab s holds rows s*16..+15 x 32 K-cols; lane l owns the 16B
// chunk {row s*16+(l&15), cols (l>>4)*8..+7} at elem s*512 + l*8
// (ds_read_b128 = 64 lanes x consecutive 16B -> conflict-free, measured 0).
// Staging per tile: 3 loads/thread (A: slab=wave, 1 load; B: slabs 2w,2w+1).
// Per iter t: read 8 frags from buf[t&1]; lgkm(0)+barrier (buffer released,
// all waves' reads done); stage tile t+2 into buf[t&1]; MFMA; then counted
// vmcnt(3) (outstanding = t+1's 3 + t+2's 3 -> wait to 3 ensures t+1
// resident) + barrier. Tail: vmcnt(0) when no t+2 stage was issued.

struct SmemW {
  alignas(16) bf16 A[2][128 * 32];   // 8 slabs x 512 elems per buffer
  alignas(16) bf16 B[2][256 * 32];   // 16 slabs per buffer
};

__device__ __forceinline__ void stageW(SmemW& sm, int bb, const bf16* A,
                                       int lda, const bf16* B, int ldb,
                                       int k0, int wave, int lane) {
  const int r16 = lane & 15, c8 = lane >> 4;
  gload16(A + (size_t)(wave * 16 + r16) * lda + k0 + c8 * 8,
          &sm.A[bb][wave * 512 + lane * 8]);
#pragma unroll
  for (int j = 0; j < 2; ++j) {
    int nb = 2 * wave + j;
    gload16(B + (size_t)(nb * 16 + r16) * ldb + k0 + c8 * 8,
            &sm.B[bb][nb * 512 + lane * 8]);
  }
}

__device__ __forceinline__ void gemmW_core(SmemW& sm, const bf16* A, int lda,
                                           const bf16* B, int ldb, int K,
                                           f32x4 acc[4][4]) {
  const int tid = threadIdx.x;
  const int wave = tid >> 6, lane = tid & 63;
  const int wr = wave >> 2, wc = wave & 3;
  const int NT = K >> 5;
  if (NT <= 0) return;

  stageW(sm, 0, A, lda, B, ldb, 0, wave, lane);
  if (NT > 1) {
    stageW(sm, 1, A, lda, B, ldb, 32, wave, lane);
    asm volatile("s_waitcnt vmcnt(3)" ::: "memory");  // tile 0 resident (own)
  } else {
    asm volatile("s_waitcnt vmcnt(0)" ::: "memory");
  }
  __builtin_amdgcn_s_barrier();  // tile 0 resident for ALL waves

  const int aoff = wr * 2048 + lane * 8;  // slabs wr*4..+3
  const int boff = wc * 2048 + lane * 8;  // slabs wc*4..+3

  for (int t = 0; t < NT; ++t) {
    const bf16* Ab = sm.A[t & 1];
    const bf16* Bb = sm.B[t & 1];
    bf16x8 av[4], bv[4];
#pragma unroll
    for (int m = 0; m < 4; ++m) av[m] = *(const bf16x8*)&Ab[aoff + m * 512];
#pragma unroll
    for (int n = 0; n < 4; ++n) bv[n] = *(const bf16x8*)&Bb[boff + n * 512];
    asm volatile("s_waitcnt lgkmcnt(0)" ::: "memory");  // my reads done
    __builtin_amdgcn_s_barrier();                       // all waves' reads done
    if (t + 2 < NT)                                     // refill freed buffer
      stageW(sm, t & 1, A, lda, B, ldb, (t + 2) * 32, wave, lane);
    __builtin_amdgcn_s_setprio(1);
#pragma unroll
    for (int m = 0; m < 4; ++m)
#pragma unroll
      for (int n = 0; n < 4; ++n)
        acc[m][n] = __builtin_amdgcn_mfma_f32_16x16x32_bf16(av[m], bv[n],
                                                            acc[m][n], 0, 0, 0);
    __builtin_amdgcn_s_setprio(0);
    if (t + 1 < NT) {
      if (t + 2 < NT)
        asm volatile("s_waitcnt vmcnt(3)" ::: "memory");  // t+1 resident
      else
        asm volatile("s_waitcnt vmcnt(0)" ::: "memory");
      __builtin_amdgcn_s_barrier();
    }
  }
}

#define EPILOGUEW_VARS                             \
  const int lane = threadIdx.x & 63;               \
  const int wave = threadIdx.x >> 6;               \
  const int wr = wave >> 2, wc = wave & 3;         \
  const int l15 = lane & 15, kl = lane >> 4;

// ---------------- elementwise kernels ----------------

__global__ __launch_bounds__(256) void k_f2b(const float* __restrict__ in,
                                             bf16* __restrict__ out) {
  int i = (blockIdx.x * 256 + threadIdx.x) * 8;
  float4 a = *(const float4*)(in + i);
  float4 b = *(const float4*)(in + i + 4);
  bf16x8 o;
  o[0] = (bf16)a.x; o[1] = (bf16)a.y; o[2] = (bf16)a.z; o[3] = (bf16)a.w;
  o[4] = (bf16)b.x; o[5] = (bf16)b.y; o[6] = (bf16)b.z; o[7] = (bf16)b.w;
  *(bf16x8*)(out + i) = o;
}

// convert two 2048x2048 fp32 weights into one contiguous bf16 buffer
__global__ __launch_bounds__(256) void k_f2b2(const float* __restrict__ in0,
                                              const float* __restrict__ in1,
                                              bf16* __restrict__ out) {
  int i = (blockIdx.x * 256 + threadIdx.x) * 8;
  const float* src = (i < D_ * D_) ? in0 : in1;
  int off = (i < D_ * D_) ? i : i - D_ * D_;
  float4 a = *(const float4*)(src + off);
  float4 b = *(const float4*)(src + off + 4);
  bf16x8 o;
  o[0] = (bf16)a.x; o[1] = (bf16)a.y; o[2] = (bf16)a.z; o[3] = (bf16)a.w;
  o[4] = (bf16)b.x; o[5] = (bf16)b.y; o[6] = (bf16)b.z; o[7] = (bf16)b.w;
  *(bf16x8*)(out + i) = o;
}

__global__ __launch_bounds__(256) void k_rms(const float* __restrict__ x,
                                             bf16* __restrict__ xn) {
  const int row = blockIdx.x;
  const int tid = threadIdx.x;
  const float* xr = x + (size_t)row * D_;
  float4 a = *(const float4*)(xr + tid * 8);
  float4 b = *(const float4*)(xr + tid * 8 + 4);
  float ss = a.x * a.x + a.y * a.y + a.z * a.z + a.w * a.w +
             b.x * b.x + b.y * b.y + b.z * b.z + b.w * b.w;
#pragma unroll
  for (int o = 32; o > 0; o >>= 1) ss += __shfl_xor(ss, o, 64);
  __shared__ float red[4];
  if ((tid & 63) == 0) red[tid >> 6] = ss;
  __syncthreads();
  float tot = red[0] + red[1] + red[2] + red[3];
  float sc = rsqrtf(tot * (1.f / D_) + 1.1920928955078125e-07f);
  bf16x8 o;
  o[0] = (bf16)(a.x * sc); o[1] = (bf16)(a.y * sc);
  o[2] = (bf16)(a.z * sc); o[3] = (bf16)(a.w * sc);
  o[4] = (bf16)(b.x * sc); o[5] = (bf16)(b.y * sc);
  o[6] = (bf16)(b.z * sc); o[7] = (bf16)(b.w * sc);
  *(bf16x8*)(xn + (size_t)row * D_ + tid * 8) = o;
}

// ---------------- big dense GEMMs (128x256 counted-vmcnt core) --------------
// grid (N/256=8, M/128=64) = 512 blocks -> 2 resident/CU.

// C = act(xn @ W^T); SMODE bit0: store normal, bit1: store transposed [B][D][N]
template <int ACT, int SMODE>
__global__ __launch_bounds__(512, 4) void k_proj2(const bf16* __restrict__ xn,
                                                  const bf16* __restrict__ W,
                                                  bf16* __restrict__ Cn,
                                                  bf16* __restrict__ Ct) {
  __shared__ SmemW sm;
  const int row0 = blockIdx.y * 128, col0 = blockIdx.x * 256;
  f32x4 acc[4][4] = {};
  gemmW_core(sm, xn + (size_t)row0 * D_, D_, W + (size_t)col0 * D_, D_, D_, acc);
  EPILOGUEW_VARS
#pragma unroll
  for (int m = 0; m < 4; ++m)
#pragma unroll
    for (int n = 0; n < 4; ++n)
#pragma unroll
      for (int j = 0; j < 4; ++j) {
        int r = row0 + wr * 64 + m * 16 + kl * 4 + j;
        int c = col0 + wc * 64 + n * 16 + l15;
        float v = acc[m][n][j];
        if (ACT == 1) v = v / (1.f + __expf(-v));        // silu
        if (ACT == 2) v = 1.f / (1.f + __expf(-v));      // sigmoid
        bf16 ob = (bf16)v;
        if (SMODE & 1) Cn[(size_t)r * D_ + c] = ob;
        if (SMODE & 2)
          Ct[((size_t)(r >> 12) * D_ + c) * NSEQ + (r & (NSEQ - 1))] = ob;
      }
}

// out = og @ Wp^T (fp32 store)
__global__ __launch_bounds__(512, 4) void k_final2(const bf16* __restrict__ og,
                                                   const bf16* __restrict__ Wp,
                                                   float* __restrict__ out) {
  __shared__ SmemW sm;
  const int row0 = blockIdx.y * 128, col0 = blockIdx.x * 256;
  f32x4 acc[4][4] = {};
  gemmW_core(sm, og + (size_t)row0 * D_, D_, Wp + (size_t)col0 * D_, D_, D_, acc);
  EPILOGUEW_VARS
#pragma unroll
  for (int m = 0; m < 4; ++m)
#pragma unroll
    for (int n = 0; n < 4; ++n)
#pragma unroll
      for (int j = 0; j < 4; ++j) {
        int r = row0 + wr * 64 + m * 16 + kl * 4 + j;
        int c = col0 + wc * 64 + n * 16 + l15;
        out[(size_t)r * D_ + c] = acc[m][n][j];
      }
}

// ---------------- chunked-recurrence kernels (128^2 core) ----------------

// s[z] = tril(q_t k_t^T), z = b*TC + t, chunk CH=1024.
__global__ __launch_bounds__(256) void k_scores(const bf16* __restrict__ q,
                                                const bf16* __restrict__ k,
                                                bf16* __restrict__ s) {
  const int z = blockIdx.z, b = z >> 2, t = z & 3;
  const int row0 = blockIdx.y * 128, col0 = blockIdx.x * 128;
  if (col0 > row0) return;  // strictly upper tile
  __shared__ SmemTiles sm;
  f32x4 acc[4][4] = {};
  gemm_core(sm, q + (size_t)(b * NSEQ + t * CH + row0) * D_, D_,
                k + (size_t)(b * NSEQ + t * CH + col0) * D_, D_, D_, acc);
  EPILOGUE_VARS
  bf16* sp = s + (size_t)z * CH * CH;
#pragma unroll
  for (int m = 0; m < 4; ++m)
#pragma unroll
    for (int n = 0; n < 4; ++n)
#pragma unroll
      for (int j = 0; j < 4; ++j) {
        int i = row0 + wr * 64 + m * 16 + kl * 4 + j;
        int jc = col0 + wc * 64 + n * 16 + l15;
        float v = (i >= jc) ? acc[m][n][j] : 0.f;
        sp[(size_t)i * CH + jc] = (bf16)v;
      }
}

// og[chunk rows] = s @ v  (intra-chunk; K trimmed to lower-tri extent)
__global__ __launch_bounds__(256) void k_ointra(const bf16* __restrict__ s,
                                                const bf16* __restrict__ vT,
                                                bf16* __restrict__ og) {
  __shared__ SmemTiles sm;
  const int z = blockIdx.z, b = z >> 2, t = z & 3;
  const int row0 = blockIdx.y * 128, col0 = blockIdx.x * 128;
  const int K = row0 + 128;
  f32x4 acc[4][4] = {};
  gemm_core(sm, s + (size_t)z * CH * CH + (size_t)row0 * CH, CH,
                vT + (size_t)b * D_ * NSEQ + (size_t)col0 * NSEQ + t * CH, NSEQ,
                K, acc);
  EPILOGUE_VARS
#pragma unroll
  for (int m = 0; m < 4; ++m)
#pragma unroll
    for (int n = 0; n < 4; ++n)
#pragma unroll
      for (int j = 0; j < 4; ++j) {
        int i = row0 + wr * 64 + m * 16 + kl * 4 + j;
        int c = col0 + wc * 64 + n * 16 + l15;
        og[(size_t)(b * NSEQ + t * CH + i) * D_ + c] = (bf16)acc[m][n][j];
      }
}

// og = (og + q_t @ kvT^T) * g   (Kin==0 for t==0: just gate)
__global__ __launch_bounds__(256) void k_ointer(const bf16* __restrict__ q,
                                                const bf16* __restrict__ kvb,
                                                const bf16* __restrict__ g,
                                                bf16* __restrict__ og, int t,
                                                int Kin) {
  __shared__ SmemTiles sm;
  const int b = blockIdx.z;
  const int row0 = blockIdx.y * 128, col0 = blockIdx.x * 128;
  f32x4 acc[4][4] = {};
  gemm_core(sm, q + (size_t)(b * NSEQ + t * CH + row0) * D_, D_,
                kvb + (size_t)b * D_ * D_ + (size_t)col0 * D_, D_, Kin, acc);
  EPILOGUE_VARS
#pragma unroll
  for (int m = 0; m < 4; ++m)
#pragma unroll
    for (int n = 0; n < 4; ++n)
#pragma unroll
      for (int j = 0; j < 4; ++j) {
        int i = row0 + wr * 64 + m * 16 + kl * 4 + j;
        int c = col0 + wc * 64 + n * 16 + l15;
        size_t idx = (size_t)(b * NSEQ + t * CH + i) * D_ + c;
        float v = ((float)og[idx] + acc[m][n][j]) * (float)g[idx];
        og[idx] = (bf16)v;
      }
}

// kvT[b][e][d] += sum_{j in chunk t} v[j][e] k[j][d]  (bf16 accumulation;
// t==0 writes without reading so no memset/poison hazard)
__global__ __launch_bounds__(256) void k_update(const bf16* __restrict__ vT,
                                                const bf16* __restrict__ kT,
                                                bf16* __restrict__ kvb, int t) {
  __shared__ SmemTiles sm;
  const int b = blockIdx.z;
  const int row0 = blockIdx.y * 128, col0 = blockIdx.x * 128;
  f32x4 acc[4][4] = {};
  gemm_core(sm, vT + (size_t)b * D_ * NSEQ + (size_t)row0 * NSEQ + t * CH, NSEQ,
                kT + (size_t)b * D_ * NSEQ + (size_t)col0 * NSEQ + t * CH, NSEQ,
                CH, acc);
  EPILOGUE_VARS
#pragma unroll
  for (int m = 0; m < 4; ++m)
#pragma unroll
    for (int n = 0; n < 4; ++n)
#pragma unroll
      for (int j = 0; j < 4; ++j) {
        int e = row0 + wr * 64 + m * 16 + kl * 4 + j;
        int d = col0 + wc * 64 + n * 16 + l15;
        size_t idx = (size_t)b * D_ * D_ + (size_t)e * D_ + d;
        float v = acc[m][n][j];
        if (t > 0) v += (float)kvb[idx];
        kvb[idx] = (bf16)v;
      }
}

// ---------------- host launch ----------------
//
// Workspace plan (~145 MiB): xn/og 32 | kT 32 | vT 32 | k 32 |
// {Wpair 16 -> s 16.78 -> kvb 16 -> Wp 8} 16.78.
// q,g live in d_out (both dead before k_final2 overwrites it).
// Lifetimes in the shared region (stream-ordered, all disjoint):
//   Wpair(Wq,Wk) [conv -> proj k] ; Wpair(Wv,Wg) [conv -> proj g] ;
//   s [scores -> ointra] ; kvb [update0 -> ointer3] ; Wp [conv -> final].

extern "C" void kernel_launch(void* const* d_in, const int* in_sizes, int n_in,
                              void* d_out, int out_size, void* d_ws, size_t ws_size,
                              hipStream_t stream) {
  (void)in_sizes; (void)n_in; (void)out_size; (void)ws_size;
  const float* x  = (const float*)d_in[0];
  const float* Wq = (const float*)d_in[1];
  const float* Wk = (const float*)d_in[2];
  const float* Wv = (const float*)d_in[3];
  const float* Wg = (const float*)d_in[4];
  const float* Wp = (const float*)d_in[5];
  float* out = (float*)d_out;

  char* p = (char*)d_ws;
  auto take = [&](size_t bytes) {
    char* r = p;
    p += (bytes + 255) & ~(size_t)255;
    return r;
  };
  const size_t MD2 = (size_t)MROWS * D_ * 2;

  bf16* xn  = (bf16*)take(MD2);                        // reused as og
  bf16* kT  = (bf16*)take(MD2);
  bf16* vT  = (bf16*)take(MD2);
  bf16* k   = (bf16*)take((size_t)MROWS * D_ * 2);     // scores operand
  char* shared = take((size_t)BATCH * TC * CH * CH * 2);  // 16.78 MiB region
  bf16* Wpair = (bf16*)shared;    // 2 weights (16 MiB), then s, then kvb, then Wp
  bf16* s    = (bf16*)shared;
  bf16* kvb  = (bf16*)shared;
  bf16* og = xn;

  bf16* q = (bf16*)d_out;
  bf16* g = (bf16*)d_out + (size_t)MROWS * D_;

  const size_t W1 = (size_t)D_ * D_;
  dim3 gpW(D_ / 256, MROWS / 128);  // (8, 64) = 512 blocks, 2/CU

  k_rms<<<MROWS, 256, 0, stream>>>(x, xn);

  k_f2b2<<<2 * (D_ * D_) / 2048, 256, 0, stream>>>(Wq, Wk, Wpair);
  k_proj2<1, 1><<<gpW, 512, 0, stream>>>(xn, Wpair, q, (bf16*)nullptr);
  k_proj2<1, 3><<<gpW, 512, 0, stream>>>(xn, Wpair + W1, k, kT);
  k_f2b2<<<2 * (D_ * D_) / 2048, 256, 0, stream>>>(Wv, Wg, Wpair);
  k_proj2<1, 2><<<gpW, 512, 0, stream>>>(xn, Wpair, (bf16*)nullptr, vT);
  k_proj2<2, 1><<<gpW, 512, 0, stream>>>(xn, Wpair + W1, g, (bf16*)nullptr);

  // intra-chunk: masked scores (lower-tri tiles only) then s @ v
  k_scores<<<dim3(CH / 128, CH / 128, BATCH * TC), 256, 0, stream>>>(q, k, s);
  k_ointra<<<dim3(D_ / 128, CH / 128, BATCH * TC), 256, 0, stream>>>(s, vT, og);

  // s dead; region becomes the bf16 KV state (written by update t=0)
  for (int t = 0; t < TC; ++t) {
    k_ointer<<<dim3(D_ / 128, CH / 128, BATCH), 256, 0, stream>>>(
        q, kvb, g, og, t, t ? D_ : 0);
    if (t < TC - 1)
      k_update<<<dim3(D_ / 128, D_ / 128, BATCH), 256, 0, stream>>>(vT, kT,
                                                                    kvb, t);
  }

  // kvb dead; region hosts the bf16 Wp
  bf16* Wpb = (bf16*)shared;
  k_f2b<<<(D_ * D_) / 2048, 256, 0, stream>>>(Wp, Wpb);
  k_final2<<<gpW, 512, 0, stream>>>(og, Wpb, out);
}